// Round 6
// baseline (207.251 us; speedup 1.0000x reference)
//
#include <hip/hip_runtime.h>
#include <hip/hip_bf16.h>
#include <math.h>

typedef __bf16 bf16_t;
typedef __bf16 bf16x8 __attribute__((ext_vector_type(8)));
typedef __bf16 bf16x4 __attribute__((ext_vector_type(4)));
typedef float  f32x4  __attribute__((ext_vector_type(4)));
typedef short  short4v __attribute__((ext_vector_type(4)));

#define NB    8
#define NC    512
#define NHW   1024
#define NHEAD 8
#define NHD   64
#define NG    32
#define NCG   16
#define NO3   1536   // 3*C
#define KVB   64     // attn K/V tile (keys per kt step)
#define NKT   16     // NHW / KVB

// ---- async global->LDS, 16B per lane. LDS dest must be wave-uniform base. ----
__device__ __forceinline__ void lds_load16(bf16_t* lds, const bf16_t* g) {
  __builtin_amdgcn_global_load_lds(
      (__attribute__((address_space(1))) unsigned int*)(g),
      (__attribute__((address_space(3))) unsigned int*)(void*)(lds),
      16, 0, 0);
}

// K=16 bf16 MFMA: C/D layout == B layout, which is what makes on-lane P reuse work.
__device__ __forceinline__ f32x4 mfma16(bf16x4 a, bf16x4 b, f32x4 c) {
#if __has_builtin(__builtin_amdgcn_mfma_f32_16x16x16bf16_1k)
  return __builtin_amdgcn_mfma_f32_16x16x16bf16_1k(
      __builtin_bit_cast(short4v, a), __builtin_bit_cast(short4v, b), c, 0, 0, 0);
#else
  f32x4 d;
  asm("v_mfma_f32_16x16x16_bf16 %0, %1, %2, %3"
      : "=v"(d) : "v"(a), "v"(b), "v"(c));
  return d;
#endif
}

// raw v_exp_f32 (libm exp2f carries range/denorm fixup code on VALU).
// R5 evidence: this alone dropped attn below the 43us fill-dispatch floor.
__device__ __forceinline__ float fexp2(float x) {
#if __has_builtin(__builtin_amdgcn_exp2f)
  return __builtin_amdgcn_exp2f(x);
#else
  return exp2f(x);
#endif
}

// =====================================================================
// Kernel 1: GroupNorm (single-pass, x tile in VGPRs) + weight fp32->bf16
// conversion merged into one launch. Blocks [0,256) = gn, [256,1280) = wconv.
// gn: one block per (b,g); thread t holds channels c=0..15 at s in [4t,4t+4).
// =====================================================================
__global__ __launch_bounds__(256)
void gnw_kernel(const float* __restrict__ x, const float* __restrict__ gw,
                const float* __restrict__ gb, bf16_t* __restrict__ xn,
                const float* __restrict__ qw, const float* __restrict__ pw,
                bf16_t* __restrict__ qwb, bf16_t* __restrict__ pwb)
{
  const int bid = blockIdx.x;
  const int tid = threadIdx.x;

  if (bid >= NB * NG) {           // ---- wconv part ----
    const int gid = (bid - NB * NG) * 256 + tid;   // one float4 each
    const int n1 = NO3 * NC / 4;                   // 196608
    float4 v; bf16x4 o;
    if (gid < n1) {
      v = ((const float4*)qw)[gid];
      o[0] = (bf16_t)v.x; o[1] = (bf16_t)v.y; o[2] = (bf16_t)v.z; o[3] = (bf16_t)v.w;
      ((bf16x4*)qwb)[gid] = o;
    } else {
      int g2 = gid - n1;                           // < 65536
      v = ((const float4*)pw)[g2];
      o[0] = (bf16_t)v.x; o[1] = (bf16_t)v.y; o[2] = (bf16_t)v.z; o[3] = (bf16_t)v.w;
      ((bf16x4*)pwb)[g2] = o;
    }
    return;
  }

  // ---- gn part ----
  const int b = bid >> 5, g = bid & 31;
  const float* xp = x + ((size_t)b * NC + g * NCG) * NHW;
  const int wave = tid >> 6, lane = tid & 63;

  // single pass: thread t loads float4 idx = c*256 + t  (c = 0..15)
  float4 v[16];
  const float4* xp4 = (const float4*)xp;
  float s1 = 0.f, s2 = 0.f;
  #pragma unroll
  for (int c = 0; c < 16; ++c) {
    v[c] = xp4[c * 256 + tid];
    s1 += v[c].x + v[c].y + v[c].z + v[c].w;
    s2 += v[c].x * v[c].x + v[c].y * v[c].y + v[c].z * v[c].z + v[c].w * v[c].w;
  }
  for (int off = 32; off > 0; off >>= 1) {
    s1 += __shfl_down(s1, off);
    s2 += __shfl_down(s2, off);
  }
  __shared__ float red[16];
  if (lane == 0) { red[wave] = s1; red[8 + wave] = s2; }
  __syncthreads();
  float tot1 = red[0] + red[1] + red[2] + red[3];
  float tot2 = red[8] + red[9] + red[10] + red[11];
  const float mean = tot1 * (1.0f / 16384.0f);
  const float var  = tot2 * (1.0f / 16384.0f) - mean * mean;
  const float rstd = rsqrtf(var + 1e-5f);

  float gam[NCG], bet[NCG];
  #pragma unroll
  for (int c = 0; c < NCG; ++c) {
    gam[c] = gw[g * NCG + c] * rstd;
    bet[c] = gb[g * NCG + c] - mean * gam[c];
  }
  bf16_t* op = xn + (size_t)b * NHW * NC + g * NCG;
  #pragma unroll
  for (int jj = 0; jj < 4; ++jj) {              // static jj -> static .x/.y/.z/.w
    int s = 4 * tid + jj;
    __align__(16) bf16_t vals[NCG];
    #pragma unroll
    for (int c = 0; c < NCG; ++c) {
      float xv = (jj == 0) ? v[c].x : (jj == 1) ? v[c].y : (jj == 2) ? v[c].z : v[c].w;
      vals[c] = (bf16_t)(xv * gam[c] + bet[c]);
    }
    *(bf16x8*)(op + (size_t)s * NC)     = *(const bf16x8*)&vals[0];
    *(bf16x8*)(op + (size_t)s * NC + 8) = *(const bf16x8*)&vals[8];
  }
}

// =====================================================================
// Kernel 3: QKV GEMM.  D[s, o] = xn[b,s,:] . w[o,:]  (M=s=1024, N=o=1536, K=512)
// Single-barrier double-buffered K-loop (BK=32, 16 steps). Epilogue scatters:
// q,k -> (b,h,s,d) [q scaled by 0.125*log2e]; v -> (b,h,d,t). grid (12, 8, 8).
// =====================================================================
__global__ __launch_bounds__(256, 2)
void qkv_gemm(const bf16_t* __restrict__ xn, const bf16_t* __restrict__ w,
              const float* __restrict__ bias,
              bf16_t* __restrict__ qbuf, bf16_t* __restrict__ kbuf, bf16_t* __restrict__ vbuf)
{
  __shared__ __align__(16) char smem[34816];  // 2x(8KB A + 8KB B); v-epilogue sC 34816B
  const int tid = threadIdx.x;
  const int wave = tid >> 6, lane = tid & 63;
  const int quad = lane >> 4, l16 = lane & 15;
  const int wm = wave >> 1, wn = wave & 1;
  const int bx = blockIdx.x, by = blockIdx.y, b = blockIdx.z;

  const bf16_t* Ap = xn + ((size_t)b * NHW + by * 128) * NC;  // rows = s
  const bf16_t* Bp = w + (size_t)bx * 128 * NC;               // rows = o

  auto stage = [&](int k0, int bufi) {
    bf16_t* sA = (bf16_t*)(smem + bufi * 16384);
    bf16_t* sB = (bf16_t*)(smem + bufi * 16384 + 8192);
    #pragma unroll
    for (int j = 0; j < 2; ++j) {
      int c = wave * 64 + j * 256 + lane;      // chunk id, 16B each
      int row = c >> 2, ko = (c & 3) * 8;
      lds_load16(sA + (size_t)(wave * 64 + j * 256) * 8, Ap + (size_t)row * 512 + k0 + ko);
      lds_load16(sB + (size_t)(wave * 64 + j * 256) * 8, Bp + (size_t)row * 512 + k0 + ko);
    }
  };

  f32x4 acc[4][4] = {};
  stage(0, 0);
  __syncthreads();
  for (int t = 0; t < 16; ++t) {
    const int cur = t & 1;
    if (t < 15) stage((t + 1) * 32, cur ^ 1);
    const bf16_t* sA = (const bf16_t*)(smem + cur * 16384);
    const bf16_t* sB = sA + 4096;
    bf16x8 af[4], bfr[4];
    #pragma unroll
    for (int mi = 0; mi < 4; ++mi)
      af[mi] = *(const bf16x8*)(sA + (wm * 64 + mi * 16 + l16) * 32 + quad * 8);
    #pragma unroll
    for (int ni = 0; ni < 4; ++ni)
      bfr[ni] = *(const bf16x8*)(sB + (wn * 64 + ni * 16 + l16) * 32 + quad * 8);
    #pragma unroll
    for (int mi = 0; mi < 4; ++mi)
      #pragma unroll
      for (int ni = 0; ni < 4; ++ni)
        acc[mi][ni] = __builtin_amdgcn_mfma_f32_16x16x32_bf16(af[mi], bfr[ni], acc[mi][ni], 0, 0, 0);
    __syncthreads();
  }

  const int obase = bx * 128 + wn * 64;
  const int sbase = by * 128 + wm * 64;
  float bv[4];
  #pragma unroll
  for (int ni = 0; ni < 4; ++ni) bv[ni] = bias[obase + ni * 16 + l16];

  if (bx < 8) {               // q (bx<4) or k region: o-contiguous layout (b,h,s,d)
    const bool isq = (bx < 4);
    bf16_t* basep = isq ? qbuf : kbuf;
    // q scale = hd^-0.5 * log2(e), so attention softmax can use native exp2
    const float scale = isq ? 0.18033688f : 1.0f;
    #pragma unroll
    for (int ni = 0; ni < 4; ++ni) {
      int o = obase + ni * 16 + l16;
      int hh = (o >> 6) & 7, dd = o & 63;
      bf16_t* dst = basep + ((size_t)(b * NHEAD + hh) * NHW) * NHD + dd;
      #pragma unroll
      for (int mi = 0; mi < 4; ++mi)
        #pragma unroll
        for (int r = 0; r < 4; ++r) {
          int s = sbase + mi * 16 + quad * 4 + r;
          dst[(size_t)s * NHD] = (bf16_t)((acc[mi][ni][r] + bv[ni]) * scale);
        }
    }
  } else {                    // v region: transpose tile via LDS -> (b,h,d,t)
    bf16_t* sC = (bf16_t*)smem;   // 128 (o) x 136 stride (s)
    __syncthreads();
    #pragma unroll
    for (int ni = 0; ni < 4; ++ni)
      #pragma unroll
      for (int mi = 0; mi < 4; ++mi)
        #pragma unroll
        for (int r = 0; r < 4; ++r)
          sC[(wn * 64 + ni * 16 + l16) * 136 + wm * 64 + mi * 16 + quad * 4 + r] =
              (bf16_t)(acc[mi][ni][r] + bv[ni]);
    __syncthreads();
    int o_local = tid >> 1, shalf = (tid & 1) << 6;
    int ov = (bx - 8) * 128 + o_local;
    int hh = ov >> 6, dd = ov & 63;
    bf16_t* dst = vbuf + ((size_t)(b * NHEAD + hh) * NHD + dd) * NHW + by * 128 + shalf;
    #pragma unroll
    for (int jj = 0; jj < 8; ++jj)
      *(bf16x8*)(dst + jj * 8) = *(const bf16x8*)&sC[o_local * 136 + shalf + jj * 8];
  }
}

// =====================================================================
// Kernel 4: flash attention, DIRECT-L2 formulation (round 6).
// R5 post-mortem: K/V per (b,h) is 128 KB each -> fully L2-resident (FETCH=12MB
// confirms), and blocks are XCD-pinned to their batch. Guide common-mistake #7:
// LDS-staging L2-fit data is pure overhead. All previous variants shared the
// staged-LDS + per-kt __syncthreads skeleton; that rendezvous x16 with vmcnt
// drain is the invariant cost. This version: NO LDS staging, NO main-loop
// barriers. Each wave reads K-frags (16B/lane, 64B/row coalesced) and V-frags
// (8B/lane, 32B runs in 64B-aligned granules) straight from L2 and runs its 16
// kt iterations fully independently; compiler is free to pipeline loads across
// iterations. One barrier at the end for the kv-half merge.
// Structure kept: 256 thr / 4 waves, wl=wave&1 (q-subtile of 32 rows),
// wg=wave>>1 (key-half: 32 of each 64-key tile), grid 1024 = (qt:16|h:8|b:8).
// S^T = K.Q^T (lane's frag all has s=l16); O^T = V^T.P^T via K=16 MFMA so P
// stays on-lane. Defer-max (T13) softmax in exp2 domain via v_exp_f32.
// =====================================================================
__global__ __launch_bounds__(256, 2)
void attn_kernel(const bf16_t* __restrict__ qbuf, const bf16_t* __restrict__ kbuf,
                 const bf16_t* __restrict__ vbuf, bf16_t* __restrict__ obuf)
{
  __shared__ __align__(16) char smem[18432];   // merge area only
  f32x4* mO = (f32x4*)smem;                    // [(wl*2+stile)*4+mi][lane] 16 KB
  float* mM = (float*)(smem + 16384);          // [(wl*2+stile)*64+lane] 1 KB
  float* mL = mM + 256;                        // 1 KB

  const int tid = threadIdx.x;
  const int wave = tid >> 6, lane = tid & 63;
  const int quad = lane >> 4, l16 = lane & 15;
  const int wl = wave & 1;        // q-subtile (32 rows); block covers 64 q-rows
  const int wg = wave >> 1;       // key-half of each 64-key tile
  const int idx = blockIdx.x;
  const int qt = idx >> 6, h = (idx >> 3) & 7, b = idx & 7;    // qt 0..15
  const size_t bh = (size_t)b * NHEAD + h;
  const bf16_t* qp = qbuf + (bh * NHW + qt * 64 + wl * 32) * NHD;
  const bf16_t* kp = kbuf + bh * NHW * NHD;    // (t, d) rows
  const bf16_t* vp = vbuf + bh * NHD * NHW;    // (d, t) rows

  // Q B-frags: B[n=s(l16)][k=d(quad*8+j)], per s-tile and per K=32 chunk
  bf16x8 qf[2][2];
  #pragma unroll
  for (int stile = 0; stile < 2; ++stile)
    #pragma unroll
    for (int kc = 0; kc < 2; ++kc)
      qf[stile][kc] = *(const bf16x8*)(qp + (size_t)(stile * 16 + l16) * NHD + kc * 32 + quad * 8);

  float m_i[2] = {-1e30f, -1e30f};
  float ll[2] = {0.f, 0.f};       // per-lane partial row-sum (quad-summed at end)
  f32x4 oacc[4][2] = {};          // O^T: [mi over d][stile]

  // per-wave row bases (loop-invariant)
  const bf16_t* krow0 = kp + (size_t)(wg * 32 + l16) * NHD;          // mt=0 rows
  const bf16_t* vrow0 = vp + (size_t)l16 * NHW + wg * 32 + quad * 4; // mi=0 rows

  for (int kt = 0; kt < NKT; ++kt) {
    // ---- S^T[t][s]: t = (wg*2+mt)*16 + quad*4 + r, s = l16 (+16*stile) ----
    f32x4 st[2][2];   // [stile][mt]
    #pragma unroll
    for (int mt = 0; mt < 2; ++mt) {
      const bf16_t* krow = krow0 + (size_t)(kt * KVB + mt * 16) * NHD;
      bf16x8 ka0 = *(const bf16x8*)(krow + quad * 8);
      bf16x8 ka1 = *(const bf16x8*)(krow + 32 + quad * 8);
      #pragma unroll
      for (int stile = 0; stile < 2; ++stile) {
        f32x4 z = {};
        z = __builtin_amdgcn_mfma_f32_16x16x32_bf16(ka0, qf[stile][0], z, 0, 0, 0);
        z = __builtin_amdgcn_mfma_f32_16x16x32_bf16(ka1, qf[stile][1], z, 0, 0, 0);
        st[stile][mt] = z;
      }
    }

    // ---- online softmax (base-2; q pre-scaled by log2e); defer-max fast path ----
    #pragma unroll
    for (int stile = 0; stile < 2; ++stile) {
      float mx = st[stile][0][0];
      #pragma unroll
      for (int mt = 0; mt < 2; ++mt)
        #pragma unroll
        for (int r = 0; r < 4; ++r) mx = fmaxf(mx, st[stile][mt][r]);
      if (!__all(mx <= m_i[stile])) {          // wave-uniform rare path
        mx = fmaxf(mx, __shfl_xor(mx, 16));
        mx = fmaxf(mx, __shfl_xor(mx, 32));
        float mnew = fmaxf(m_i[stile], mx);
        float alpha = fexp2(m_i[stile] - mnew);
        m_i[stile] = mnew;
        ll[stile] *= alpha;
        #pragma unroll
        for (int mi = 0; mi < 4; ++mi)
          #pragma unroll
          for (int r = 0; r < 4; ++r) oacc[mi][stile][r] *= alpha;
      }
      float rs = 0.f;
      #pragma unroll
      for (int mt = 0; mt < 2; ++mt)
        #pragma unroll
        for (int r = 0; r < 4; ++r) {
          float p = fexp2(st[stile][mt][r] - m_i[stile]);
          rs += p;
          st[stile][mt][r] = p;
        }
      ll[stile] += rs;
    }

    // ---- O^T += V^T . P^T (K=16 per mt); P B-frag = lane's own st values ----
    #pragma unroll
    for (int mt = 0; mt < 2; ++mt) {
      bf16x4 pb[2];
      #pragma unroll
      for (int stile = 0; stile < 2; ++stile) {
        pb[stile][0] = (bf16_t)st[stile][mt][0];
        pb[stile][1] = (bf16_t)st[stile][mt][1];
        pb[stile][2] = (bf16_t)st[stile][mt][2];
        pb[stile][3] = (bf16_t)st[stile][mt][3];
      }
      #pragma unroll
      for (int mi = 0; mi < 4; ++mi) {
        bf16x4 va = *(const bf16x4*)(vrow0 + (size_t)mi * 16 * NHW + kt * KVB + mt * 16);
        oacc[mi][0] = mfma16(va, pb[0], oacc[mi][0]);
        oacc[mi][1] = mfma16(va, pb[1], oacc[mi][1]);
      }
    }
  }

  // finalize: per-lane partial l -> per-column l (sum over quads), once.
  float l_i[2];
  #pragma unroll
  for (int stile = 0; stile < 2; ++stile) {
    float rs = ll[stile];
    rs += __shfl_xor(rs, 16);
    rs += __shfl_xor(rs, 32);
    l_i[stile] = rs;
  }

  // ---- merge the two key-half online-softmax states (waves w and w+2) ----
  if (wg == 1) {
    #pragma unroll
    for (int stile = 0; stile < 2; ++stile) {
      mM[(wl * 2 + stile) * 64 + lane] = m_i[stile];
      mL[(wl * 2 + stile) * 64 + lane] = l_i[stile];
      #pragma unroll
      for (int mi = 0; mi < 4; ++mi)
        mO[((wl * 2 + stile) * 4 + mi) * 64 + lane] = oacc[mi][stile];
    }
  }
  __syncthreads();
  if (wg == 0) {
    // epilogue: O^T C-layout: row = d = mi*16 + quad*4 + r, col = s = l16
    #pragma unroll
    for (int stile = 0; stile < 2; ++stile) {
      float mB = mM[(wl * 2 + stile) * 64 + lane];
      float lB = mL[(wl * 2 + stile) * 64 + lane];
      float mS = fmaxf(m_i[stile], mB);
      float aA = fexp2(m_i[stile] - mS);
      float aB = fexp2(mB - mS);
      float inv = 1.0f / (l_i[stile] * aA + lB * aB);
      int s = qt * 64 + wl * 32 + stile * 16 + l16;
      bf16_t* orow = obuf + ((size_t)b * NHW + s) * NC + h * NHD;
      #pragma unroll
      for (int mi = 0; mi < 4; ++mi) {
        f32x4 oB = mO[((wl * 2 + stile) * 4 + mi) * 64 + lane];
        __align__(8) bf16_t o4[4];
        #pragma unroll
        for (int r = 0; r < 4; ++r)
          o4[r] = (bf16_t)((oacc[mi][stile][r] * aA + oB[r] * aB) * inv);
        *(bf16x4*)(orow + mi * 16 + quad * 4) = *(const bf16x4*)o4;
      }
    }
  }
}

// =====================================================================
// Kernel 5: proj GEMM + bias + residual. D[co, s] = w[co,:] . ob[b,s,:]
// 64co x 128s tiles -> grid (8 s, 8 co, 8 b) = 512 blocks = 2/CU, plus
// the single-barrier double-buffered K-loop (24 KB LDS). fp32 out, coalesced.
// =====================================================================
__global__ __launch_bounds__(256, 2)
void proj_gemm(const bf16_t* __restrict__ ob, const bf16_t* __restrict__ w,
               const float* __restrict__ bias, const float* __restrict__ x,
               float* __restrict__ out)
{
  __shared__ __align__(16) char smem[24576];   // 2 x (4KB A + 8KB B)
  const int tid = threadIdx.x;
  const int wave = tid >> 6, lane = tid & 63;
  const int quad = lane >> 4, l16 = lane & 15;
  const int wm = wave & 1, wn = wave >> 1;     // wm: co-half(32), wn: s-half(64)
  const int bx = blockIdx.x, by = blockIdx.y, b = blockIdx.z;

  const bf16_t* Ap = w + (size_t)by * 64 * NC;                // 64 co rows
  const bf16_t* Bp = ob + ((size_t)b * NHW + bx * 128) * NC;  // 128 s rows

  auto stage = [&](int k0, int bufi) {
    bf16_t* sA = (bf16_t*)(smem + bufi * 12288);
    bf16_t* sB = (bf16_t*)(smem + bufi * 12288 + 4096);
    {
      int c = wave * 64 + lane;                // A: 256 chunks, 1 inst/wave
      int row = c >> 2, ko = (c & 3) * 8;
      lds_load16(sA + (size_t)(wave * 64) * 8, Ap + (size_t)row * 512 + k0 + ko);
    }
    #pragma unroll
    for (int j = 0; j < 2; ++j) {              // B: 512 chunks, 2 insts/wave
      int c = wave * 64 + j * 256 + lane;
      int row = c >> 2, ko = (c & 3) * 8;
      lds_load16(sB + (size_t)(wave * 64 + j * 256) * 8, Bp + (size_t)row * 512 + k0 + ko);
    }
  };

  f32x4 acc[2][4] = {};
  stage(0, 0);
  __syncthreads();
  for (int t = 0; t < 16; ++t) {
    const int cur = t & 1;
    if (t < 15) stage((t + 1) * 32, cur ^ 1);
    const bf16_t* sA = (const bf16_t*)(smem + cur * 12288);
    const bf16_t* sB = sA + 2048;
    bf16x8 af[2], bfr[4];
    #pragma unroll
    for (int mi = 0; mi < 2; ++mi)
      af[mi] = *(const bf16x8*)(sA + (wm * 32 + mi * 16 + l16) * 32 + quad * 8);
    #pragma unroll
    for (int ni = 0; ni < 4; ++ni)
      bfr[ni] = *(const bf16x8*)(sB + (wn * 64 + ni * 16 + l16) * 32 + quad * 8);
    #pragma unroll
    for (int mi = 0; mi < 2; ++mi)
      #pragma unroll
      for (int ni = 0; ni < 4; ++ni)
        acc[mi][ni] = __builtin_amdgcn_mfma_f32_16x16x32_bf16(af[mi], bfr[ni], acc[mi][ni], 0, 0, 0);
    __syncthreads();
  }

  const int cobase = by * 64 + wm * 32;
  const int sbase  = bx * 128 + wn * 64;
  #pragma unroll
  for (int mi = 0; mi < 2; ++mi)
    #pragma unroll
    for (int r = 0; r < 4; ++r) {
      int co = cobase + mi * 16 + quad * 4 + r;
      float pb = bias[co];
      const float* xrow = x + ((size_t)b * NC + co) * NHW;
      float* orow = out + ((size_t)b * NC + co) * NHW;
      #pragma unroll
      for (int ni = 0; ni < 4; ++ni) {
        int s = sbase + ni * 16 + l16;
        orow[s] = acc[mi][ni][r] + pb + xrow[s];
      }
    }
}

// =====================================================================
extern "C" void kernel_launch(void* const* d_in, const int* in_sizes, int n_in,
                              void* d_out, int out_size, void* d_ws, size_t ws_size,
                              hipStream_t stream)
{
  const float* x      = (const float*)d_in[0];
  const float* gn_w   = (const float*)d_in[1];
  const float* gn_b   = (const float*)d_in[2];
  const float* qkv_w  = (const float*)d_in[3];
  const float* qkv_b  = (const float*)d_in[4];
  const float* proj_w = (const float*)d_in[5];
  const float* proj_b = (const float*)d_in[6];
  float* out = (float*)d_out;

  char* ws = (char*)d_ws;
  // xn (B,HW,C) bf16 reused later as attention output obuf (B,HW,C) bf16
  bf16_t* xn   = (bf16_t*)(ws);                       //  8 MiB
  bf16_t* qwb  = (bf16_t*)(ws + 8388608);             //  1.5 MiB (1536x512)
  bf16_t* pwb  = (bf16_t*)(ws + 9961472);             //  0.5 MiB (512x512)
  bf16_t* qbuf = (bf16_t*)(ws + 10485760);            //  8 MiB (b,h,s,d)
  bf16_t* kbuf = (bf16_t*)(ws + 18874368);            //  8 MiB (b,h,s,d)
  bf16_t* vbuf = (bf16_t*)(ws + 27262976);            //  8 MiB (b,h,d,t)
  bf16_t* obuf = xn;                                  // reuse: xn dead after qkv_gemm

  gnw_kernel<<<dim3(NB * NG + 1024), dim3(256), 0, stream>>>(
      x, gn_w, gn_b, xn, qkv_w, proj_w, qwb, pwb);
  qkv_gemm<<<dim3(12, 8, NB), dim3(256), 0, stream>>>(xn, qwb, qkv_b, qbuf, kbuf, vbuf);
  attn_kernel<<<dim3(1024), dim3(256), 0, stream>>>(qbuf, kbuf, vbuf, obuf);
  proj_gemm<<<dim3(8, 8, NB), dim3(256), 0, stream>>>(obuf, pwb, proj_b, x, out);
}

// Round 7
// 152.498 us; speedup vs baseline: 1.3590x; 1.3590x over previous
//
#include <hip/hip_runtime.h>
#include <hip/hip_bf16.h>
#include <math.h>

typedef __bf16 bf16_t;
typedef __bf16 bf16x8 __attribute__((ext_vector_type(8)));
typedef __bf16 bf16x4 __attribute__((ext_vector_type(4)));
typedef float  f32x4  __attribute__((ext_vector_type(4)));
typedef short  short4v __attribute__((ext_vector_type(4)));

#define NB    8
#define NC    512
#define NHW   1024
#define NHEAD 8
#define NHD   64
#define NG    32
#define NCG   16
#define NO3   1536   // 3*C
#define KVB   64     // attn K/V tile (keys per kt step)
#define NKT   16     // NHW / KVB

// ---- async global->LDS, 16B per lane. LDS dest must be wave-uniform base. ----
__device__ __forceinline__ void lds_load16(bf16_t* lds, const bf16_t* g) {
  __builtin_amdgcn_global_load_lds(
      (__attribute__((address_space(1))) unsigned int*)(g),
      (__attribute__((address_space(3))) unsigned int*)(void*)(lds),
      16, 0, 0);
}

// K=16 bf16 MFMA: C/D layout == B layout, which is what makes on-lane P reuse work.
__device__ __forceinline__ f32x4 mfma16(bf16x4 a, bf16x4 b, f32x4 c) {
#if __has_builtin(__builtin_amdgcn_mfma_f32_16x16x16bf16_1k)
  return __builtin_amdgcn_mfma_f32_16x16x16bf16_1k(
      __builtin_bit_cast(short4v, a), __builtin_bit_cast(short4v, b), c, 0, 0, 0);
#else
  f32x4 d;
  asm("v_mfma_f32_16x16x16_bf16 %0, %1, %2, %3"
      : "=v"(d) : "v"(a), "v"(b), "v"(c));
  return d;
#endif
}

// raw v_exp_f32 (libm exp2f carries range/denorm fixup code on VALU).
// R5 evidence: this alone dropped attn 49 -> 40us.
__device__ __forceinline__ float fexp2(float x) {
#if __has_builtin(__builtin_amdgcn_exp2f)
  return __builtin_amdgcn_exp2f(x);
#else
  return exp2f(x);
#endif
}

// =====================================================================
// Kernel 1: GroupNorm (single-pass, x tile in VGPRs) + weight fp32->bf16
// conversion merged into one launch. Blocks [0,256) = gn, [256,1280) = wconv.
// =====================================================================
__global__ __launch_bounds__(256)
void gnw_kernel(const float* __restrict__ x, const float* __restrict__ gw,
                const float* __restrict__ gb, bf16_t* __restrict__ xn,
                const float* __restrict__ qw, const float* __restrict__ pw,
                bf16_t* __restrict__ qwb, bf16_t* __restrict__ pwb)
{
  const int bid = blockIdx.x;
  const int tid = threadIdx.x;

  if (bid >= NB * NG) {           // ---- wconv part ----
    const int gid = (bid - NB * NG) * 256 + tid;   // one float4 each
    const int n1 = NO3 * NC / 4;                   // 196608
    float4 v; bf16x4 o;
    if (gid < n1) {
      v = ((const float4*)qw)[gid];
      o[0] = (bf16_t)v.x; o[1] = (bf16_t)v.y; o[2] = (bf16_t)v.z; o[3] = (bf16_t)v.w;
      ((bf16x4*)qwb)[gid] = o;
    } else {
      int g2 = gid - n1;                           // < 65536
      v = ((const float4*)pw)[g2];
      o[0] = (bf16_t)v.x; o[1] = (bf16_t)v.y; o[2] = (bf16_t)v.z; o[3] = (bf16_t)v.w;
      ((bf16x4*)pwb)[g2] = o;
    }
    return;
  }

  // ---- gn part ----
  const int b = bid >> 5, g = bid & 31;
  const float* xp = x + ((size_t)b * NC + g * NCG) * NHW;
  const int wave = tid >> 6, lane = tid & 63;

  // single pass: thread t loads float4 idx = c*256 + t  (c = 0..15)
  float4 v[16];
  const float4* xp4 = (const float4*)xp;
  float s1 = 0.f, s2 = 0.f;
  #pragma unroll
  for (int c = 0; c < 16; ++c) {
    v[c] = xp4[c * 256 + tid];
    s1 += v[c].x + v[c].y + v[c].z + v[c].w;
    s2 += v[c].x * v[c].x + v[c].y * v[c].y + v[c].z * v[c].z + v[c].w * v[c].w;
  }
  for (int off = 32; off > 0; off >>= 1) {
    s1 += __shfl_down(s1, off);
    s2 += __shfl_down(s2, off);
  }
  __shared__ float red[16];
  if (lane == 0) { red[wave] = s1; red[8 + wave] = s2; }
  __syncthreads();
  float tot1 = red[0] + red[1] + red[2] + red[3];
  float tot2 = red[8] + red[9] + red[10] + red[11];
  const float mean = tot1 * (1.0f / 16384.0f);
  const float var  = tot2 * (1.0f / 16384.0f) - mean * mean;
  const float rstd = rsqrtf(var + 1e-5f);

  float gam[NCG], bet[NCG];
  #pragma unroll
  for (int c = 0; c < NCG; ++c) {
    gam[c] = gw[g * NCG + c] * rstd;
    bet[c] = gb[g * NCG + c] - mean * gam[c];
  }
  bf16_t* op = xn + (size_t)b * NHW * NC + g * NCG;
  #pragma unroll
  for (int jj = 0; jj < 4; ++jj) {              // static jj -> static .x/.y/.z/.w
    int s = 4 * tid + jj;
    __align__(16) bf16_t vals[NCG];
    #pragma unroll
    for (int c = 0; c < NCG; ++c) {
      float xv = (jj == 0) ? v[c].x : (jj == 1) ? v[c].y : (jj == 2) ? v[c].z : v[c].w;
      vals[c] = (bf16_t)(xv * gam[c] + bet[c]);
    }
    *(bf16x8*)(op + (size_t)s * NC)     = *(const bf16x8*)&vals[0];
    *(bf16x8*)(op + (size_t)s * NC + 8) = *(const bf16x8*)&vals[8];
  }
}

// =====================================================================
// Kernel 3: QKV GEMM.  D[s, o] = xn[b,s,:] . w[o,:]  (M=s=1024, N=o=1536, K=512)
// Single-barrier double-buffered K-loop (BK=32, 16 steps). R7: bounds (256,3)
// -> VGPR cap 170 (live state ~130, no spill) and guaranteed 3 blocks/CU
// (was 2) for better barrier/latency coverage. Epilogue scatters: q,k ->
// (b,h,s,d) [q scaled by 0.125*log2e]; v -> (b,h,d,t). grid (12, 8, 8).
// =====================================================================
__global__ __launch_bounds__(256, 3)
void qkv_gemm(const bf16_t* __restrict__ xn, const bf16_t* __restrict__ w,
              const float* __restrict__ bias,
              bf16_t* __restrict__ qbuf, bf16_t* __restrict__ kbuf, bf16_t* __restrict__ vbuf)
{
  __shared__ __align__(16) char smem[34816];  // 2x(8KB A + 8KB B); v-epilogue sC 34816B
  const int tid = threadIdx.x;
  const int wave = tid >> 6, lane = tid & 63;
  const int quad = lane >> 4, l16 = lane & 15;
  const int wm = wave >> 1, wn = wave & 1;
  const int bx = blockIdx.x, by = blockIdx.y, b = blockIdx.z;

  const bf16_t* Ap = xn + ((size_t)b * NHW + by * 128) * NC;  // rows = s
  const bf16_t* Bp = w + (size_t)bx * 128 * NC;               // rows = o

  auto stage = [&](int k0, int bufi) {
    bf16_t* sA = (bf16_t*)(smem + bufi * 16384);
    bf16_t* sB = (bf16_t*)(smem + bufi * 16384 + 8192);
    #pragma unroll
    for (int j = 0; j < 2; ++j) {
      int c = wave * 64 + j * 256 + lane;      // chunk id, 16B each
      int row = c >> 2, ko = (c & 3) * 8;
      lds_load16(sA + (size_t)(wave * 64 + j * 256) * 8, Ap + (size_t)row * 512 + k0 + ko);
      lds_load16(sB + (size_t)(wave * 64 + j * 256) * 8, Bp + (size_t)row * 512 + k0 + ko);
    }
  };

  f32x4 acc[4][4] = {};
  stage(0, 0);
  __syncthreads();
  for (int t = 0; t < 16; ++t) {
    const int cur = t & 1;
    if (t < 15) stage((t + 1) * 32, cur ^ 1);
    const bf16_t* sA = (const bf16_t*)(smem + cur * 16384);
    const bf16_t* sB = sA + 4096;
    bf16x8 af[4], bfr[4];
    #pragma unroll
    for (int mi = 0; mi < 4; ++mi)
      af[mi] = *(const bf16x8*)(sA + (wm * 64 + mi * 16 + l16) * 32 + quad * 8);
    #pragma unroll
    for (int ni = 0; ni < 4; ++ni)
      bfr[ni] = *(const bf16x8*)(sB + (wn * 64 + ni * 16 + l16) * 32 + quad * 8);
    #pragma unroll
    for (int mi = 0; mi < 4; ++mi)
      #pragma unroll
      for (int ni = 0; ni < 4; ++ni)
        acc[mi][ni] = __builtin_amdgcn_mfma_f32_16x16x32_bf16(af[mi], bfr[ni], acc[mi][ni], 0, 0, 0);
    __syncthreads();
  }

  const int obase = bx * 128 + wn * 64;
  const int sbase = by * 128 + wm * 64;
  float bv[4];
  #pragma unroll
  for (int ni = 0; ni < 4; ++ni) bv[ni] = bias[obase + ni * 16 + l16];

  if (bx < 8) {               // q (bx<4) or k region: o-contiguous layout (b,h,s,d)
    const bool isq = (bx < 4);
    bf16_t* basep = isq ? qbuf : kbuf;
    // q scale = hd^-0.5 * log2(e), so attention softmax can use native exp2
    const float scale = isq ? 0.18033688f : 1.0f;
    #pragma unroll
    for (int ni = 0; ni < 4; ++ni) {
      int o = obase + ni * 16 + l16;
      int hh = (o >> 6) & 7, dd = o & 63;
      bf16_t* dst = basep + ((size_t)(b * NHEAD + hh) * NHW) * NHD + dd;
      #pragma unroll
      for (int mi = 0; mi < 4; ++mi)
        #pragma unroll
        for (int r = 0; r < 4; ++r) {
          int s = sbase + mi * 16 + quad * 4 + r;
          dst[(size_t)s * NHD] = (bf16_t)((acc[mi][ni][r] + bv[ni]) * scale);
        }
    }
  } else {                    // v region: transpose tile via LDS -> (b,h,d,t)
    bf16_t* sC = (bf16_t*)smem;   // 128 (o) x 136 stride (s)
    __syncthreads();
    #pragma unroll
    for (int ni = 0; ni < 4; ++ni)
      #pragma unroll
      for (int mi = 0; mi < 4; ++mi)
        #pragma unroll
        for (int r = 0; r < 4; ++r)
          sC[(wn * 64 + ni * 16 + l16) * 136 + wm * 64 + mi * 16 + quad * 4 + r] =
              (bf16_t)(acc[mi][ni][r] + bv[ni]);
    __syncthreads();
    int o_local = tid >> 1, shalf = (tid & 1) << 6;
    int ov = (bx - 8) * 128 + o_local;
    int hh = ov >> 6, dd = ov & 63;
    bf16_t* dst = vbuf + ((size_t)(b * NHEAD + hh) * NHD + dd) * NHW + by * 128 + shalf;
    #pragma unroll
    for (int jj = 0; jj < 8; ++jj)
      *(bf16x8*)(dst + jj * 8) = *(const bf16x8*)&sC[o_local * 136 + shalf + jj * 8];
  }
}

// =====================================================================
// Kernel 4: flash attention — R5 version restored verbatim (proven 40us).
// R6 post-mortem: direct-L2 regressed 2.4x (VGPR sunk to 52, no LDS broadcast
// reuse -> raw L2 latency chains). LDS staging stays: it is also the 4-way
// wave broadcast of K/V, not just a cache.
// Staged gll double-buffer, 1 barrier/kt, T2 content-swizzle via pre-swizzled
// source, T13 defer-max, T5 setprio, v_exp_f32 softmax.
// =====================================================================
__global__ __launch_bounds__(256, 2)
void attn_kernel(const bf16_t* __restrict__ qbuf, const bf16_t* __restrict__ kbuf,
                 const bf16_t* __restrict__ vbuf, bf16_t* __restrict__ obuf)
{
  __shared__ __align__(16) char smem[32768];
  f32x4* mO = (f32x4*)smem;                 // merge (only after final barrier)
  float* mM = (float*)(smem + 16384);
  float* mL = (float*)(smem + 17408);

  const int tid = threadIdx.x;
  const int wave = tid >> 6, lane = tid & 63;
  const int quad = lane >> 4, l16 = lane & 15;
  const int wl = wave & 1;        // q-subtile (32 rows); block covers 64 q-rows
  const int wg = wave >> 1;       // key-half of each 64-key tile
  const int idx = blockIdx.x;
  const int qt = idx >> 6, h = (idx >> 3) & 7, b = idx & 7;    // qt 0..15
  const size_t bh = (size_t)b * NHEAD + h;
  const bf16_t* qp = qbuf + (bh * NHW + qt * 64 + wl * 32) * NHD;
  const char* kp = (const char*)(kbuf + bh * NHW * NHD);
  const char* vp = (const char*)(vbuf + bh * NHD * NHW);

  const int r8 = lane >> 3;
  const int swc = (((lane & 7) << 4)) ^ (r8 << 4);   // pre-swizzled byte col

  bf16x8 qf[2][2];
  #pragma unroll
  for (int stile = 0; stile < 2; ++stile)
    #pragma unroll
    for (int kc = 0; kc < 2; ++kc)
      qf[stile][kc] = *(const bf16x8*)(qp + (size_t)(stile * 16 + l16) * NHD + kc * 32 + quad * 8);

  float m_i[2] = {-1e30f, -1e30f};
  float ll[2] = {0.f, 0.f};
  f32x4 oacc[4][2] = {};

  #pragma unroll
  for (int j = 0; j < 2; ++j) {
    int i = wave * 2 + j;
    const char* kg = kp + ((size_t)(i * 8 + r8) * NHD) * 2 + swc;
    lds_load16((bf16_t*)(smem + i * 1024), (const bf16_t*)kg);
    const char* vg = vp + ((size_t)(i * 8 + r8) * NHW) * 2 + swc;
    lds_load16((bf16_t*)(smem + 8192 + i * 1024), (const bf16_t*)vg);
  }
  __syncthreads();

  const int swr = (l16 & 7) << 4;

  for (int kt = 0; kt < NKT; ++kt) {
    const int cur = kt & 1;
    const char* Kb = smem + cur * 16384;
    const char* Vb = Kb + 8192;
    if (kt < NKT - 1) {
      char* Kn = smem + (cur ^ 1) * 16384;
      #pragma unroll
      for (int j = 0; j < 2; ++j) {
        int i = wave * 2 + j;
        const char* kg = kp + ((size_t)((kt + 1) * KVB + i * 8 + r8) * NHD) * 2 + swc;
        lds_load16((bf16_t*)(Kn + i * 1024), (const bf16_t*)kg);
        const char* vg = vp + ((size_t)(i * 8 + r8) * NHW + (kt + 1) * KVB) * 2 + swc;
        lds_load16((bf16_t*)(Kn + 8192 + i * 1024), (const bf16_t*)vg);
      }
    }

    f32x4 st[2][2];
    __builtin_amdgcn_s_setprio(1);
    #pragma unroll
    for (int mt = 0; mt < 2; ++mt) {
      const int mtg = wg * 2 + mt;
      const char* krow = Kb + (mtg * 16 + l16) * 128;
      bf16x8 ka0 = *(const bf16x8*)(krow + ((quad * 16) ^ swr));
      bf16x8 ka1 = *(const bf16x8*)(krow + ((64 + quad * 16) ^ swr));
      #pragma unroll
      for (int stile = 0; stile < 2; ++stile) {
        f32x4 z = {};
        z = __builtin_amdgcn_mfma_f32_16x16x32_bf16(ka0, qf[stile][0], z, 0, 0, 0);
        z = __builtin_amdgcn_mfma_f32_16x16x32_bf16(ka1, qf[stile][1], z, 0, 0, 0);
        st[stile][mt] = z;
      }
    }
    __builtin_amdgcn_s_setprio(0);

    #pragma unroll
    for (int stile = 0; stile < 2; ++stile) {
      float mx = st[stile][0][0];
      #pragma unroll
      for (int mt = 0; mt < 2; ++mt)
        #pragma unroll
        for (int r = 0; r < 4; ++r) mx = fmaxf(mx, st[stile][mt][r]);
      if (!__all(mx <= m_i[stile])) {
        mx = fmaxf(mx, __shfl_xor(mx, 16));
        mx = fmaxf(mx, __shfl_xor(mx, 32));
        float mnew = fmaxf(m_i[stile], mx);
        float alpha = fexp2(m_i[stile] - mnew);
        m_i[stile] = mnew;
        ll[stile] *= alpha;
        #pragma unroll
        for (int mi = 0; mi < 4; ++mi)
          #pragma unroll
          for (int r = 0; r < 4; ++r) oacc[mi][stile][r] *= alpha;
      }
      float rs = 0.f;
      #pragma unroll
      for (int mt = 0; mt < 2; ++mt)
        #pragma unroll
        for (int r = 0; r < 4; ++r) {
          float p = fexp2(st[stile][mt][r] - m_i[stile]);
          rs += p;
          st[stile][mt][r] = p;
        }
      ll[stile] += rs;
    }

    __builtin_amdgcn_s_setprio(1);
    #pragma unroll
    for (int mt = 0; mt < 2; ++mt) {
      const int mtg = wg * 2 + mt;
      bf16x4 pb[2];
      #pragma unroll
      for (int stile = 0; stile < 2; ++stile) {
        pb[stile][0] = (bf16_t)st[stile][mt][0];
        pb[stile][1] = (bf16_t)st[stile][mt][1];
        pb[stile][2] = (bf16_t)st[stile][mt][2];
        pb[stile][3] = (bf16_t)st[stile][mt][3];
      }
      #pragma unroll
      for (int mi = 0; mi < 4; ++mi) {
        const char* vrow = Vb + (mi * 16 + l16) * 128;
        bf16x4 va = *(const bf16x4*)(vrow + ((mtg * 32 + quad * 8) ^ swr));
        oacc[mi][0] = mfma16(va, pb[0], oacc[mi][0]);
        oacc[mi][1] = mfma16(va, pb[1], oacc[mi][1]);
      }
    }
    __builtin_amdgcn_s_setprio(0);
    __syncthreads();
  }

  float l_i[2];
  #pragma unroll
  for (int stile = 0; stile < 2; ++stile) {
    float rs = ll[stile];
    rs += __shfl_xor(rs, 16);
    rs += __shfl_xor(rs, 32);
    l_i[stile] = rs;
  }

  if (wg == 1) {
    #pragma unroll
    for (int stile = 0; stile < 2; ++stile) {
      mM[(wl * 2 + stile) * 64 + lane] = m_i[stile];
      mL[(wl * 2 + stile) * 64 + lane] = l_i[stile];
      #pragma unroll
      for (int mi = 0; mi < 4; ++mi)
        mO[((wl * 2 + stile) * 4 + mi) * 64 + lane] = oacc[mi][stile];
    }
  }
  __syncthreads();
  if (wg == 0) {
    #pragma unroll
    for (int stile = 0; stile < 2; ++stile) {
      float mB = mM[(wl * 2 + stile) * 64 + lane];
      float lB = mL[(wl * 2 + stile) * 64 + lane];
      float mS = fmaxf(m_i[stile], mB);
      float aA = fexp2(m_i[stile] - mS);
      float aB = fexp2(mB - mS);
      float inv = 1.0f / (l_i[stile] * aA + lB * aB);
      int s = qt * 64 + wl * 32 + stile * 16 + l16;
      bf16_t* orow = obuf + ((size_t)b * NHW + s) * NC + h * NHD;
      #pragma unroll
      for (int mi = 0; mi < 4; ++mi) {
        f32x4 oB = mO[((wl * 2 + stile) * 4 + mi) * 64 + lane];
        __align__(8) bf16_t o4[4];
        #pragma unroll
        for (int r = 0; r < 4; ++r)
          o4[r] = (bf16_t)((oacc[mi][stile][r] * aA + oB[r] * aB) * inv);
        *(bf16x4*)(orow + mi * 16 + quad * 4) = *(const bf16x4*)o4;
      }
    }
  }
}

// =====================================================================
// Kernel 5: proj GEMM + bias + residual. D[co, s] = w[co,:] . ob[b,s,:]
// 64co x 128s tiles -> grid (8 s, 8 co, 8 b) = 512 blocks = 2/CU, plus
// the single-barrier double-buffered K-loop (24 KB LDS). fp32 out, coalesced.
// =====================================================================
__global__ __launch_bounds__(256, 2)
void proj_gemm(const bf16_t* __restrict__ ob, const bf16_t* __restrict__ w,
               const float* __restrict__ bias, const float* __restrict__ x,
               float* __restrict__ out)
{
  __shared__ __align__(16) char smem[24576];   // 2 x (4KB A + 8KB B)
  const int tid = threadIdx.x;
  const int wave = tid >> 6, lane = tid & 63;
  const int quad = lane >> 4, l16 = lane & 15;
  const int wm = wave & 1, wn = wave >> 1;     // wm: co-half(32), wn: s-half(64)
  const int bx = blockIdx.x, by = blockIdx.y, b = blockIdx.z;

  const bf16_t* Ap = w + (size_t)by * 64 * NC;                // 64 co rows
  const bf16_t* Bp = ob + ((size_t)b * NHW + bx * 128) * NC;  // 128 s rows

  auto stage = [&](int k0, int bufi) {
    bf16_t* sA = (bf16_t*)(smem + bufi * 12288);
    bf16_t* sB = (bf16_t*)(smem + bufi * 12288 + 4096);
    {
      int c = wave * 64 + lane;                // A: 256 chunks, 1 inst/wave
      int row = c >> 2, ko = (c & 3) * 8;
      lds_load16(sA + (size_t)(wave * 64) * 8, Ap + (size_t)row * 512 + k0 + ko);
    }
    #pragma unroll
    for (int j = 0; j < 2; ++j) {              // B: 512 chunks, 2 insts/wave
      int c = wave * 64 + j * 256 + lane;
      int row = c >> 2, ko = (c & 3) * 8;
      lds_load16(sB + (size_t)(wave * 64 + j * 256) * 8, Bp + (size_t)row * 512 + k0 + ko);
    }
  };

  f32x4 acc[2][4] = {};
  stage(0, 0);
  __syncthreads();
  for (int t = 0; t < 16; ++t) {
    const int cur = t & 1;
    if (t < 15) stage((t + 1) * 32, cur ^ 1);
    const bf16_t* sA = (const bf16_t*)(smem + cur * 12288);
    const bf16_t* sB = sA + 2048;
    bf16x8 af[2], bfr[4];
    #pragma unroll
    for (int mi = 0; mi < 2; ++mi)
      af[mi] = *(const bf16x8*)(sA + (wm * 32 + mi * 16 + l16) * 32 + quad * 8);
    #pragma unroll
    for (int ni = 0; ni < 4; ++ni)
      bfr[ni] = *(const bf16x8*)(sB + (wn * 64 + ni * 16 + l16) * 32 + quad * 8);
    #pragma unroll
    for (int mi = 0; mi < 2; ++mi)
      #pragma unroll
      for (int ni = 0; ni < 4; ++ni)
        acc[mi][ni] = __builtin_amdgcn_mfma_f32_16x16x32_bf16(af[mi], bfr[ni], acc[mi][ni], 0, 0, 0);
    __syncthreads();
  }

  const int cobase = by * 64 + wm * 32;
  const int sbase  = bx * 128 + wn * 64;
  #pragma unroll
  for (int mi = 0; mi < 2; ++mi)
    #pragma unroll
    for (int r = 0; r < 4; ++r) {
      int co = cobase + mi * 16 + quad * 4 + r;
      float pb = bias[co];
      const float* xrow = x + ((size_t)b * NC + co) * NHW;
      float* orow = out + ((size_t)b * NC + co) * NHW;
      #pragma unroll
      for (int ni = 0; ni < 4; ++ni) {
        int s = sbase + ni * 16 + l16;
        orow[s] = acc[mi][ni][r] + pb + xrow[s];
      }
    }
}

// =====================================================================
extern "C" void kernel_launch(void* const* d_in, const int* in_sizes, int n_in,
                              void* d_out, int out_size, void* d_ws, size_t ws_size,
                              hipStream_t stream)
{
  const float* x      = (const float*)d_in[0];
  const float* gn_w   = (const float*)d_in[1];
  const float* gn_b   = (const float*)d_in[2];
  const float* qkv_w  = (const float*)d_in[3];
  const float* qkv_b  = (const float*)d_in[4];
  const float* proj_w = (const float*)d_in[5];
  const float* proj_b = (const float*)d_in[6];
  float* out = (float*)d_out;

  char* ws = (char*)d_ws;
  // xn (B,HW,C) bf16 reused later as attention output obuf (B,HW,C) bf16
  bf16_t* xn   = (bf16_t*)(ws);                       //  8 MiB
  bf16_t* qwb  = (bf16_t*)(ws + 8388608);             //  1.5 MiB (1536x512)
  bf16_t* pwb  = (bf16_t*)(ws + 9961472);             //  0.5 MiB (512x512)
  bf16_t* qbuf = (bf16_t*)(ws + 10485760);            //  8 MiB (b,h,s,d)
  bf16_t* kbuf = (bf16_t*)(ws + 18874368);            //  8 MiB (b,h,s,d)
  bf16_t* vbuf = (bf16_t*)(ws + 27262976);            //  8 MiB (b,h,d,t)
  bf16_t* obuf = xn;                                  // reuse: xn dead after qkv_gemm

  gnw_kernel<<<dim3(NB * NG + 1024), dim3(256), 0, stream>>>(
      x, gn_w, gn_b, xn, qkv_w, proj_w, qwb, pwb);
  qkv_gemm<<<dim3(12, 8, NB), dim3(256), 0, stream>>>(xn, qwb, qkv_b, qbuf, kbuf, vbuf);
  attn_kernel<<<dim3(1024), dim3(256), 0, stream>>>(qbuf, kbuf, vbuf, obuf);
  proj_gemm<<<dim3(8, 8, NB), dim3(256), 0, stream>>>(obuf, pwb, proj_b, x, out);
}

// Round 8
// 148.588 us; speedup vs baseline: 1.3948x; 1.0263x over previous
//
#include <hip/hip_runtime.h>
#include <hip/hip_bf16.h>
#include <math.h>

typedef __bf16 bf16_t;
typedef __bf16 bf16x8 __attribute__((ext_vector_type(8)));
typedef __bf16 bf16x4 __attribute__((ext_vector_type(4)));
typedef float  f32x4  __attribute__((ext_vector_type(4)));
typedef short  short4v __attribute__((ext_vector_type(4)));

#define NB    8
#define NC    512
#define NHW   1024
#define NHEAD 8
#define NHD   64
#define NG    32
#define NCG   16
#define NO3   1536   // 3*C
#define KVB   64     // attn K/V tile (keys per kt step)
#define NKT   16     // NHW / KVB

// ---- async global->LDS, 16B per lane. LDS dest must be wave-uniform base. ----
__device__ __forceinline__ void lds_load16(bf16_t* lds, const bf16_t* g) {
  __builtin_amdgcn_global_load_lds(
      (__attribute__((address_space(1))) unsigned int*)(g),
      (__attribute__((address_space(3))) unsigned int*)(void*)(lds),
      16, 0, 0);
}

// K=16 bf16 MFMA: C/D layout == B layout, which is what makes on-lane P reuse work.
__device__ __forceinline__ f32x4 mfma16(bf16x4 a, bf16x4 b, f32x4 c) {
#if __has_builtin(__builtin_amdgcn_mfma_f32_16x16x16bf16_1k)
  return __builtin_amdgcn_mfma_f32_16x16x16bf16_1k(
      __builtin_bit_cast(short4v, a), __builtin_bit_cast(short4v, b), c, 0, 0, 0);
#else
  f32x4 d;
  asm("v_mfma_f32_16x16x16_bf16 %0, %1, %2, %3"
      : "=v"(d) : "v"(a), "v"(b), "v"(c));
  return d;
#endif
}

// raw v_exp_f32 (libm exp2f carries range/denorm fixup code on VALU).
// R5 evidence: this alone dropped attn 49 -> 44us.
__device__ __forceinline__ float fexp2(float x) {
#if __has_builtin(__builtin_amdgcn_exp2f)
  return __builtin_amdgcn_exp2f(x);
#else
  return exp2f(x);
#endif
}

// =====================================================================
// Kernel 1: GroupNorm (single-pass, x tile in VGPRs) + weight fp32->bf16
// conversion merged into one launch. Blocks [0,256) = gn, [256,1280) = wconv.
// =====================================================================
__global__ __launch_bounds__(256)
void gnw_kernel(const float* __restrict__ x, const float* __restrict__ gw,
                const float* __restrict__ gb, bf16_t* __restrict__ xn,
                const float* __restrict__ qw, const float* __restrict__ pw,
                bf16_t* __restrict__ qwb, bf16_t* __restrict__ pwb)
{
  const int bid = blockIdx.x;
  const int tid = threadIdx.x;

  if (bid >= NB * NG) {           // ---- wconv part ----
    const int gid = (bid - NB * NG) * 256 + tid;   // one float4 each
    const int n1 = NO3 * NC / 4;                   // 196608
    float4 v; bf16x4 o;
    if (gid < n1) {
      v = ((const float4*)qw)[gid];
      o[0] = (bf16_t)v.x; o[1] = (bf16_t)v.y; o[2] = (bf16_t)v.z; o[3] = (bf16_t)v.w;
      ((bf16x4*)qwb)[gid] = o;
    } else {
      int g2 = gid - n1;                           // < 65536
      v = ((const float4*)pw)[g2];
      o[0] = (bf16_t)v.x; o[1] = (bf16_t)v.y; o[2] = (bf16_t)v.z; o[3] = (bf16_t)v.w;
      ((bf16x4*)pwb)[g2] = o;
    }
    return;
  }

  // ---- gn part ----
  const int b = bid >> 5, g = bid & 31;
  const float* xp = x + ((size_t)b * NC + g * NCG) * NHW;
  const int wave = tid >> 6, lane = tid & 63;

  // single pass: thread t loads float4 idx = c*256 + t  (c = 0..15)
  float4 v[16];
  const float4* xp4 = (const float4*)xp;
  float s1 = 0.f, s2 = 0.f;
  #pragma unroll
  for (int c = 0; c < 16; ++c) {
    v[c] = xp4[c * 256 + tid];
    s1 += v[c].x + v[c].y + v[c].z + v[c].w;
    s2 += v[c].x * v[c].x + v[c].y * v[c].y + v[c].z * v[c].z + v[c].w * v[c].w;
  }
  for (int off = 32; off > 0; off >>= 1) {
    s1 += __shfl_down(s1, off);
    s2 += __shfl_down(s2, off);
  }
  __shared__ float red[16];
  if (lane == 0) { red[wave] = s1; red[8 + wave] = s2; }
  __syncthreads();
  float tot1 = red[0] + red[1] + red[2] + red[3];
  float tot2 = red[8] + red[9] + red[10] + red[11];
  const float mean = tot1 * (1.0f / 16384.0f);
  const float var  = tot2 * (1.0f / 16384.0f) - mean * mean;
  const float rstd = rsqrtf(var + 1e-5f);

  float gam[NCG], bet[NCG];
  #pragma unroll
  for (int c = 0; c < NCG; ++c) {
    gam[c] = gw[g * NCG + c] * rstd;
    bet[c] = gb[g * NCG + c] - mean * gam[c];
  }
  bf16_t* op = xn + (size_t)b * NHW * NC + g * NCG;
  #pragma unroll
  for (int jj = 0; jj < 4; ++jj) {              // static jj -> static .x/.y/.z/.w
    int s = 4 * tid + jj;
    __align__(16) bf16_t vals[NCG];
    #pragma unroll
    for (int c = 0; c < NCG; ++c) {
      float xv = (jj == 0) ? v[c].x : (jj == 1) ? v[c].y : (jj == 2) ? v[c].z : v[c].w;
      vals[c] = (bf16_t)(xv * gam[c] + bet[c]);
    }
    *(bf16x8*)(op + (size_t)s * NC)     = *(const bf16x8*)&vals[0];
    *(bf16x8*)(op + (size_t)s * NC + 8) = *(const bf16x8*)&vals[8];
  }
}

// =====================================================================
// Kernel 3: QKV GEMM.  D[s, o] = xn[b,s,:] . w[o,:]  (M=s=1024, N=o=1536, K=512)
// R8: BK=64 (8 K-steps, was 16) -> half the barrier drains, 32 MFMA/phase.
// LDS 64KB double-buffer; (256,2) keeps 2 blocks/CU (128KB <= 160KB).
// T2 XOR-swizzle via pre-swizzled gll SOURCE (8-chunk-row involution, same
// pattern as attn staging): fragment ds_reads go 8/16-way -> 2-way (free).
// LDS[row][c7] = G[row][c7 ^ (row&7)]; read col-chunk x at byte
// row*128 + ((x*16) ^ ((l16&7)<<4)). Global coalescing preserved (permutation
// stays within each 128B row). Epilogue unchanged. grid (12, 8, 8).
// =====================================================================
__global__ __launch_bounds__(256, 2)
void qkv_gemm(const bf16_t* __restrict__ xn, const bf16_t* __restrict__ w,
              const float* __restrict__ bias,
              bf16_t* __restrict__ qbuf, bf16_t* __restrict__ kbuf, bf16_t* __restrict__ vbuf)
{
  __shared__ __align__(16) char smem[65536];  // 2 x (16KB A + 16KB B)
  const int tid = threadIdx.x;
  const int wave = tid >> 6, lane = tid & 63;
  const int quad = lane >> 4, l16 = lane & 15;
  const int wm = wave >> 1, wn = wave & 1;
  const int bx = blockIdx.x, by = blockIdx.y, b = blockIdx.z;

  const bf16_t* Ap = xn + ((size_t)b * NHW + by * 128) * NC;  // rows = s
  const bf16_t* Bp = w + (size_t)bx * 128 * NC;               // rows = o

  // stage one 128x64 tile of A and B: 1024 chunks each (8 chunks/row),
  // source chunk-col pre-swizzled by XOR with (row&7).
  auto stage = [&](int k0, int bufi) {
    bf16_t* sA = (bf16_t*)(smem + bufi * 32768);
    bf16_t* sB = (bf16_t*)(smem + bufi * 32768 + 16384);
    #pragma unroll
    for (int j = 0; j < 4; ++j) {
      int c = wave * 64 + j * 256 + lane;
      int row = c >> 3, ko = ((c ^ (c >> 3)) & 7) * 8;
      lds_load16(sA + (size_t)(wave * 64 + j * 256) * 8, Ap + (size_t)row * 512 + k0 + ko);
      lds_load16(sB + (size_t)(wave * 64 + j * 256) * 8, Bp + (size_t)row * 512 + k0 + ko);
    }
  };

  f32x4 acc[4][4] = {};
  stage(0, 0);
  __syncthreads();
  const int swr = (l16 & 7) << 4;
  for (int t = 0; t < 8; ++t) {
    const int cur = t & 1;
    if (t < 7) stage((t + 1) * 64, cur ^ 1);
    const char* sA = smem + cur * 32768;
    const char* sB = sA + 16384;
    #pragma unroll
    for (int kc = 0; kc < 2; ++kc) {
      bf16x8 af[4], bfr[4];
      #pragma unroll
      for (int mi = 0; mi < 4; ++mi)
        af[mi] = *(const bf16x8*)(sA + (wm * 64 + mi * 16 + l16) * 128 + ((kc * 64 + quad * 16) ^ swr));
      #pragma unroll
      for (int ni = 0; ni < 4; ++ni)
        bfr[ni] = *(const bf16x8*)(sB + (wn * 64 + ni * 16 + l16) * 128 + ((kc * 64 + quad * 16) ^ swr));
      #pragma unroll
      for (int mi = 0; mi < 4; ++mi)
        #pragma unroll
        for (int ni = 0; ni < 4; ++ni)
          acc[mi][ni] = __builtin_amdgcn_mfma_f32_16x16x32_bf16(af[mi], bfr[ni], acc[mi][ni], 0, 0, 0);
    }
    __syncthreads();
  }

  const int obase = bx * 128 + wn * 64;
  const int sbase = by * 128 + wm * 64;
  float bv[4];
  #pragma unroll
  for (int ni = 0; ni < 4; ++ni) bv[ni] = bias[obase + ni * 16 + l16];

  if (bx < 8) {               // q (bx<4) or k region: o-contiguous layout (b,h,s,d)
    const bool isq = (bx < 4);
    bf16_t* basep = isq ? qbuf : kbuf;
    // q scale = hd^-0.5 * log2(e), so attention softmax can use native exp2
    const float scale = isq ? 0.18033688f : 1.0f;
    #pragma unroll
    for (int ni = 0; ni < 4; ++ni) {
      int o = obase + ni * 16 + l16;
      int hh = (o >> 6) & 7, dd = o & 63;
      bf16_t* dst = basep + ((size_t)(b * NHEAD + hh) * NHW) * NHD + dd;
      #pragma unroll
      for (int mi = 0; mi < 4; ++mi)
        #pragma unroll
        for (int r = 0; r < 4; ++r) {
          int s = sbase + mi * 16 + quad * 4 + r;
          dst[(size_t)s * NHD] = (bf16_t)((acc[mi][ni][r] + bv[ni]) * scale);
        }
    }
  } else {                    // v region: transpose tile via LDS -> (b,h,d,t)
    bf16_t* sC = (bf16_t*)smem;   // 128 (o) x 136 stride (s)
    __syncthreads();
    #pragma unroll
    for (int ni = 0; ni < 4; ++ni)
      #pragma unroll
      for (int mi = 0; mi < 4; ++mi)
        #pragma unroll
        for (int r = 0; r < 4; ++r)
          sC[(wn * 64 + ni * 16 + l16) * 136 + wm * 64 + mi * 16 + quad * 4 + r] =
              (bf16_t)(acc[mi][ni][r] + bv[ni]);
    __syncthreads();
    int o_local = tid >> 1, shalf = (tid & 1) << 6;
    int ov = (bx - 8) * 128 + o_local;
    int hh = ov >> 6, dd = ov & 63;
    bf16_t* dst = vbuf + ((size_t)(b * NHEAD + hh) * NHD + dd) * NHW + by * 128 + shalf;
    #pragma unroll
    for (int jj = 0; jj < 8; ++jj)
      *(bf16x8*)(dst + jj * 8) = *(const bf16x8*)&sC[o_local * 136 + shalf + jj * 8];
  }
}

// =====================================================================
// Kernel 4: flash attention — R5/R7 version, FROZEN (43.8us measured).
// Staged gll double-buffer, 1 barrier/kt, T2 content-swizzle via pre-swizzled
// source, T13 defer-max, T5 setprio, v_exp_f32 softmax.
// =====================================================================
__global__ __launch_bounds__(256, 2)
void attn_kernel(const bf16_t* __restrict__ qbuf, const bf16_t* __restrict__ kbuf,
                 const bf16_t* __restrict__ vbuf, bf16_t* __restrict__ obuf)
{
  __shared__ __align__(16) char smem[32768];
  f32x4* mO = (f32x4*)smem;                 // merge (only after final barrier)
  float* mM = (float*)(smem + 16384);
  float* mL = (float*)(smem + 17408);

  const int tid = threadIdx.x;
  const int wave = tid >> 6, lane = tid & 63;
  const int quad = lane >> 4, l16 = lane & 15;
  const int wl = wave & 1;        // q-subtile (32 rows); block covers 64 q-rows
  const int wg = wave >> 1;       // key-half of each 64-key tile
  const int idx = blockIdx.x;
  const int qt = idx >> 6, h = (idx >> 3) & 7, b = idx & 7;    // qt 0..15
  const size_t bh = (size_t)b * NHEAD + h;
  const bf16_t* qp = qbuf + (bh * NHW + qt * 64 + wl * 32) * NHD;
  const char* kp = (const char*)(kbuf + bh * NHW * NHD);
  const char* vp = (const char*)(vbuf + bh * NHD * NHW);

  const int r8 = lane >> 3;
  const int swc = (((lane & 7) << 4)) ^ (r8 << 4);   // pre-swizzled byte col

  bf16x8 qf[2][2];
  #pragma unroll
  for (int stile = 0; stile < 2; ++stile)
    #pragma unroll
    for (int kc = 0; kc < 2; ++kc)
      qf[stile][kc] = *(const bf16x8*)(qp + (size_t)(stile * 16 + l16) * NHD + kc * 32 + quad * 8);

  float m_i[2] = {-1e30f, -1e30f};
  float ll[2] = {0.f, 0.f};
  f32x4 oacc[4][2] = {};

  #pragma unroll
  for (int j = 0; j < 2; ++j) {
    int i = wave * 2 + j;
    const char* kg = kp + ((size_t)(i * 8 + r8) * NHD) * 2 + swc;
    lds_load16((bf16_t*)(smem + i * 1024), (const bf16_t*)kg);
    const char* vg = vp + ((size_t)(i * 8 + r8) * NHW) * 2 + swc;
    lds_load16((bf16_t*)(smem + 8192 + i * 1024), (const bf16_t*)vg);
  }
  __syncthreads();

  const int swr = (l16 & 7) << 4;

  for (int kt = 0; kt < NKT; ++kt) {
    const int cur = kt & 1;
    const char* Kb = smem + cur * 16384;
    const char* Vb = Kb + 8192;
    if (kt < NKT - 1) {
      char* Kn = smem + (cur ^ 1) * 16384;
      #pragma unroll
      for (int j = 0; j < 2; ++j) {
        int i = wave * 2 + j;
        const char* kg = kp + ((size_t)((kt + 1) * KVB + i * 8 + r8) * NHD) * 2 + swc;
        lds_load16((bf16_t*)(Kn + i * 1024), (const bf16_t*)kg);
        const char* vg = vp + ((size_t)(i * 8 + r8) * NHW + (kt + 1) * KVB) * 2 + swc;
        lds_load16((bf16_t*)(Kn + 8192 + i * 1024), (const bf16_t*)vg);
      }
    }

    f32x4 st[2][2];
    __builtin_amdgcn_s_setprio(1);
    #pragma unroll
    for (int mt = 0; mt < 2; ++mt) {
      const int mtg = wg * 2 + mt;
      const char* krow = Kb + (mtg * 16 + l16) * 128;
      bf16x8 ka0 = *(const bf16x8*)(krow + ((quad * 16) ^ swr));
      bf16x8 ka1 = *(const bf16x8*)(krow + ((64 + quad * 16) ^ swr));
      #pragma unroll
      for (int stile = 0; stile < 2; ++stile) {
        f32x4 z = {};
        z = __builtin_amdgcn_mfma_f32_16x16x32_bf16(ka0, qf[stile][0], z, 0, 0, 0);
        z = __builtin_amdgcn_mfma_f32_16x16x32_bf16(ka1, qf[stile][1], z, 0, 0, 0);
        st[stile][mt] = z;
      }
    }
    __builtin_amdgcn_s_setprio(0);

    #pragma unroll
    for (int stile = 0; stile < 2; ++stile) {
      float mx = st[stile][0][0];
      #pragma unroll
      for (int mt = 0; mt < 2; ++mt)
        #pragma unroll
        for (int r = 0; r < 4; ++r) mx = fmaxf(mx, st[stile][mt][r]);
      if (!__all(mx <= m_i[stile])) {
        mx = fmaxf(mx, __shfl_xor(mx, 16));
        mx = fmaxf(mx, __shfl_xor(mx, 32));
        float mnew = fmaxf(m_i[stile], mx);
        float alpha = fexp2(m_i[stile] - mnew);
        m_i[stile] = mnew;
        ll[stile] *= alpha;
        #pragma unroll
        for (int mi = 0; mi < 4; ++mi)
          #pragma unroll
          for (int r = 0; r < 4; ++r) oacc[mi][stile][r] *= alpha;
      }
      float rs = 0.f;
      #pragma unroll
      for (int mt = 0; mt < 2; ++mt)
        #pragma unroll
        for (int r = 0; r < 4; ++r) {
          float p = fexp2(st[stile][mt][r] - m_i[stile]);
          rs += p;
          st[stile][mt][r] = p;
        }
      ll[stile] += rs;
    }

    __builtin_amdgcn_s_setprio(1);
    #pragma unroll
    for (int mt = 0; mt < 2; ++mt) {
      const int mtg = wg * 2 + mt;
      bf16x4 pb[2];
      #pragma unroll
      for (int stile = 0; stile < 2; ++stile) {
        pb[stile][0] = (bf16_t)st[stile][mt][0];
        pb[stile][1] = (bf16_t)st[stile][mt][1];
        pb[stile][2] = (bf16_t)st[stile][mt][2];
        pb[stile][3] = (bf16_t)st[stile][mt][3];
      }
      #pragma unroll
      for (int mi = 0; mi < 4; ++mi) {
        const char* vrow = Vb + (mi * 16 + l16) * 128;
        bf16x4 va = *(const bf16x4*)(vrow + ((mtg * 32 + quad * 8) ^ swr));
        oacc[mi][0] = mfma16(va, pb[0], oacc[mi][0]);
        oacc[mi][1] = mfma16(va, pb[1], oacc[mi][1]);
      }
    }
    __builtin_amdgcn_s_setprio(0);
    __syncthreads();
  }

  float l_i[2];
  #pragma unroll
  for (int stile = 0; stile < 2; ++stile) {
    float rs = ll[stile];
    rs += __shfl_xor(rs, 16);
    rs += __shfl_xor(rs, 32);
    l_i[stile] = rs;
  }

  if (wg == 1) {
    #pragma unroll
    for (int stile = 0; stile < 2; ++stile) {
      mM[(wl * 2 + stile) * 64 + lane] = m_i[stile];
      mL[(wl * 2 + stile) * 64 + lane] = l_i[stile];
      #pragma unroll
      for (int mi = 0; mi < 4; ++mi)
        mO[((wl * 2 + stile) * 4 + mi) * 64 + lane] = oacc[mi][stile];
    }
  }
  __syncthreads();
  if (wg == 0) {
    #pragma unroll
    for (int stile = 0; stile < 2; ++stile) {
      float mB = mM[(wl * 2 + stile) * 64 + lane];
      float lB = mL[(wl * 2 + stile) * 64 + lane];
      float mS = fmaxf(m_i[stile], mB);
      float aA = fexp2(m_i[stile] - mS);
      float aB = fexp2(mB - mS);
      float inv = 1.0f / (l_i[stile] * aA + lB * aB);
      int s = qt * 64 + wl * 32 + stile * 16 + l16;
      bf16_t* orow = obuf + ((size_t)b * NHW + s) * NC + h * NHD;
      #pragma unroll
      for (int mi = 0; mi < 4; ++mi) {
        f32x4 oB = mO[((wl * 2 + stile) * 4 + mi) * 64 + lane];
        __align__(8) bf16_t o4[4];
        #pragma unroll
        for (int r = 0; r < 4; ++r)
          o4[r] = (bf16_t)((oacc[mi][stile][r] * aA + oB[r] * aB) * inv);
        *(bf16x4*)(orow + mi * 16 + quad * 4) = *(const bf16x4*)o4;
      }
    }
  }
}

// =====================================================================
// Kernel 5: proj GEMM + bias + residual. D[co, s] = w[co,:] . ob[b,s,:]
// R8: BK=64 (8 steps) + pre-swizzled-source staging, same as qkv. LDS 48KB
// double-buffer; (256,2) -> 96KB/CU. 64co x 128s tiles, grid (8,8,8) = 2/CU.
// =====================================================================
__global__ __launch_bounds__(256, 2)
void proj_gemm(const bf16_t* __restrict__ ob, const bf16_t* __restrict__ w,
               const float* __restrict__ bias, const float* __restrict__ x,
               float* __restrict__ out)
{
  __shared__ __align__(16) char smem[49152];   // 2 x (8KB A + 16KB B)
  const int tid = threadIdx.x;
  const int wave = tid >> 6, lane = tid & 63;
  const int quad = lane >> 4, l16 = lane & 15;
  const int wm = wave & 1, wn = wave >> 1;     // wm: co-half(32), wn: s-half(64)
  const int bx = blockIdx.x, by = blockIdx.y, b = blockIdx.z;

  const bf16_t* Ap = w + (size_t)by * 64 * NC;                // 64 co rows
  const bf16_t* Bp = ob + ((size_t)b * NHW + bx * 128) * NC;  // 128 s rows

  auto stage = [&](int k0, int bufi) {
    bf16_t* sA = (bf16_t*)(smem + bufi * 24576);
    bf16_t* sB = (bf16_t*)(smem + bufi * 24576 + 8192);
    #pragma unroll
    for (int j = 0; j < 2; ++j) {              // A: 512 chunks (64 rows x 8)
      int c = wave * 64 + j * 256 + lane;
      int row = c >> 3, ko = ((c ^ (c >> 3)) & 7) * 8;
      lds_load16(sA + (size_t)(wave * 64 + j * 256) * 8, Ap + (size_t)row * 512 + k0 + ko);
    }
    #pragma unroll
    for (int j = 0; j < 4; ++j) {              // B: 1024 chunks (128 rows x 8)
      int c = wave * 64 + j * 256 + lane;
      int row = c >> 3, ko = ((c ^ (c >> 3)) & 7) * 8;
      lds_load16(sB + (size_t)(wave * 64 + j * 256) * 8, Bp + (size_t)row * 512 + k0 + ko);
    }
  };

  f32x4 acc[2][4] = {};
  stage(0, 0);
  __syncthreads();
  const int swr = (l16 & 7) << 4;
  for (int t = 0; t < 8; ++t) {
    const int cur = t & 1;
    if (t < 7) stage((t + 1) * 64, cur ^ 1);
    const char* sA = smem + cur * 24576;
    const char* sB = sA + 8192;
    #pragma unroll
    for (int kc = 0; kc < 2; ++kc) {
      bf16x8 af[2], bfr[4];
      #pragma unroll
      for (int mi = 0; mi < 2; ++mi)
        af[mi] = *(const bf16x8*)(sA + (wm * 32 + mi * 16 + l16) * 128 + ((kc * 64 + quad * 16) ^ swr));
      #pragma unroll
      for (int ni = 0; ni < 4; ++ni)
        bfr[ni] = *(const bf16x8*)(sB + (wn * 64 + ni * 16 + l16) * 128 + ((kc * 64 + quad * 16) ^ swr));
      #pragma unroll
      for (int mi = 0; mi < 2; ++mi)
        #pragma unroll
        for (int ni = 0; ni < 4; ++ni)
          acc[mi][ni] = __builtin_amdgcn_mfma_f32_16x16x32_bf16(af[mi], bfr[ni], acc[mi][ni], 0, 0, 0);
    }
    __syncthreads();
  }

  const int cobase = by * 64 + wm * 32;
  const int sbase  = bx * 128 + wn * 64;
  #pragma unroll
  for (int mi = 0; mi < 2; ++mi)
    #pragma unroll
    for (int r = 0; r < 4; ++r) {
      int co = cobase + mi * 16 + quad * 4 + r;
      float pb = bias[co];
      const float* xrow = x + ((size_t)b * NC + co) * NHW;
      float* orow = out + ((size_t)b * NC + co) * NHW;
      #pragma unroll
      for (int ni = 0; ni < 4; ++ni) {
        int s = sbase + ni * 16 + l16;
        orow[s] = acc[mi][ni][r] + pb + xrow[s];
      }
    }
}

// =====================================================================
extern "C" void kernel_launch(void* const* d_in, const int* in_sizes, int n_in,
                              void* d_out, int out_size, void* d_ws, size_t ws_size,
                              hipStream_t stream)
{
  const float* x      = (const float*)d_in[0];
  const float* gn_w   = (const float*)d_in[1];
  const float* gn_b   = (const float*)d_in[2];
  const float* qkv_w  = (const float*)d_in[3];
  const float* qkv_b  = (const float*)d_in[4];
  const float* proj_w = (const float*)d_in[5];
  const float* proj_b = (const float*)d_in[6];
  float* out = (float*)d_out;

  char* ws = (char*)d_ws;
  // xn (B,HW,C) bf16 reused later as attention output obuf (B,HW,C) bf16
  bf16_t* xn   = (bf16_t*)(ws);                       //  8 MiB
  bf16_t* qwb  = (bf16_t*)(ws + 8388608);             //  1.5 MiB (1536x512)
  bf16_t* pwb  = (bf16_t*)(ws + 9961472);             //  0.5 MiB (512x512)
  bf16_t* qbuf = (bf16_t*)(ws + 10485760);            //  8 MiB (b,h,s,d)
  bf16_t* kbuf = (bf16_t*)(ws + 18874368);            //  8 MiB (b,h,s,d)
  bf16_t* vbuf = (bf16_t*)(ws + 27262976);            //  8 MiB (b,h,d,t)
  bf16_t* obuf = xn;                                  // reuse: xn dead after qkv_gemm

  gnw_kernel<<<dim3(NB * NG + 1024), dim3(256), 0, stream>>>(
      x, gn_w, gn_b, xn, qkv_w, proj_w, qwb, pwb);
  qkv_gemm<<<dim3(12, 8, NB), dim3(256), 0, stream>>>(xn, qwb, qkv_b, qbuf, kbuf, vbuf);
  attn_kernel<<<dim3(1024), dim3(256), 0, stream>>>(qbuf, kbuf, vbuf, obuf);
  proj_gemm<<<dim3(8, 8, NB), dim3(256), 0, stream>>>(obuf, pwb, proj_b, x, out);
}